// Round 12
// baseline (199.312 us; speedup 1.0000x reference)
//
#include <hip/hip_runtime.h>

// MultiHeadSelfAttention: B=4, N=2048, D=1024, H=16, Hd=64
// QKV GEMM: 256x256 8-phase schedule (T2 swizzle + T3/T4 counted-vmcnt +
// T5 setprio), 8 waves, 128KB LDS, raw s_barrier. Attention: R11 kernel
// (LDS-shared K/V, max-free softmax w/ hw v_exp_f32, V-permuted PV).
// Proj: 128^2 2-phase gemm (unchanged).

typedef __attribute__((ext_vector_type(8))) short bf16x8;
typedef __attribute__((ext_vector_type(4))) short s16x4;
typedef __attribute__((ext_vector_type(4))) float f32x4;
typedef __attribute__((ext_vector_type(16))) float f32x16;
typedef __attribute__((ext_vector_type(4))) unsigned u32x4;

#define LOG2E 1.44269504088896340736f

__device__ static inline short f2bf(float f) {
  unsigned u = __builtin_bit_cast(unsigned, f);
  unsigned r = (u + 0x7fffu + ((u >> 16) & 1u)) >> 16;
  return (short)r;
}
__device__ static inline unsigned cvtpk_bf16(float lo, float hi) {
  unsigned r;
  asm("v_cvt_pk_bf16_f32 %0, %1, %2" : "=v"(r) : "v"(lo), "v"(hi));
  return r;
}
__device__ static inline float exp2_hw(float x) {
#if __has_builtin(__builtin_amdgcn_exp2f)
  return __builtin_amdgcn_exp2f(x);
#else
  float r;
  asm("v_exp_f32 %0, %1" : "=v"(r) : "v"(x));
  return r;
#endif
}

__device__ static inline void gload_lds16(const void* g, void* l) {
  __builtin_amdgcn_global_load_lds(
      (const __attribute__((address_space(1))) void*)g,
      (__attribute__((address_space(3))) void*)l, 16, 0, 0);
}

// ---------------- fp32 -> bf16 convert ----------------
__global__ void cvt_f32_bf16(const float* __restrict__ in, short* __restrict__ out, int n4) {
  int i = blockIdx.x * 256 + threadIdx.x;
  if (i < n4) {
    float4 v = ((const float4*)in)[i];
    s16x4 o4 = { f2bf(v.x), f2bf(v.y), f2bf(v.z), f2bf(v.w) };
    ((s16x4*)out)[i] = o4;
  }
}

// ---------------- QKV GEMM: 256x256 tile, BK=64, 8-phase ----------------
// A = xb [8192][1024], B = wqkv [3072][1024] (B^T gemm). Grid (12, 32).
// LDS: buf b at b*65536: A [256][64] bf16 (+0), B [256][64] (+32768).
// Row = 128B; chunk swizzle: slot = chunk ^ (row&7). 8 waves = 2(M) x 4(N);
// wave owns 128x64 out = 8 M-frags x 4 N-frags (16x16).
__global__ __launch_bounds__(512, 2) void gemm_qkv(
    const short* __restrict__ A, const short* __restrict__ Bm,
    const float* __restrict__ bias,
    short* __restrict__ qo, short* __restrict__ ko, short* __restrict__ vto) {
  __shared__ __align__(16) char smem[131072];
  const int tid = threadIdx.x, lane = tid & 63, w = tid >> 6;
  const int wm = w >> 2, wn = w & 3;
  const int bn = blockIdx.x, bm = blockIdx.y;
  const int fr = lane & 15;
  // ds_read chunk offsets (bytes) for k-half 0/1: slot = kgrp ^ (row&7), row&7 = lane&7
  const int cb0 = ((((lane >> 4))     ^ (lane & 7)) << 4);
  const int cb1 = ((((lane >> 4)) + 4 ^ (lane & 7)) << 4);

  char* ldsA0 = smem;
  char* ldsB0 = smem + 32768;
  char* ldsA1 = smem + 65536;
  char* ldsB1 = smem + 98304;

  const short* Ag = A + (size_t)(bm * 256) * 1024;
  const short* Bg = Bm + (size_t)(bn * 256) * 1024;

  // stage one half-tile (128 rows x 64 cols) = 2 x gload_lds16 per thread.
  // LDS dest linear (wave-uniform base + lane*16); source pre-inverse-swizzled.
  auto STAGE = [&](const short* __restrict__ mg, int kt, int half, char* ldsmat) {
#pragma unroll
    for (int sw = 0; sw < 2; ++sw) {
      int r = half * 128 + sw * 64 + w * 8 + (lane >> 3);
      gload_lds16(mg + (size_t)r * 1024 + (kt & 15) * 64 + ((lane & 7) ^ (lane >> 3)) * 8,
                  ldsmat + (half * 128 + sw * 64 + w * 8) * 128);
    }
  };

  f32x4 acc[8][4];
  const f32x4 z4 = {0.f, 0.f, 0.f, 0.f};
#pragma unroll
  for (int i = 0; i < 8; ++i)
#pragma unroll
    for (int j = 0; j < 4; ++j) acc[i][j] = z4;

  bf16x8 a[4][2], b[2][2];

  // prologue: prime stream through "prev-iter ph7": buf0 full + A(1)h0
  STAGE(Ag, 0, 0, ldsA0);
  STAGE(Ag, 0, 1, ldsA0);
  STAGE(Bg, 0, 0, ldsB0);
  STAGE(Bg, 0, 1, ldsB0);
  STAGE(Ag, 1, 0, ldsA1);
  asm volatile("s_waitcnt vmcnt(2)" ::: "memory");
  __builtin_amdgcn_s_barrier();

#define PHASE(BUF, MH, NH, RDA, SG, SLDS, STILE, SHALF, W2)                    \
  {                                                                            \
    const char* Ab_ = smem + (BUF) * 65536;                                    \
    const char* Bb_ = Ab_ + 32768;                                             \
    if (RDA) {                                                                 \
      _Pragma("unroll")                                                        \
      for (int mf = 0; mf < 4; ++mf) {                                         \
        const char* ar = Ab_ + (wm * 128 + (MH) * 64 + mf * 16 + fr) * 128;    \
        a[mf][0] = *(const bf16x8*)(ar + cb0);                                 \
        a[mf][1] = *(const bf16x8*)(ar + cb1);                                 \
      }                                                                        \
    }                                                                          \
    _Pragma("unroll")                                                          \
    for (int nf = 0; nf < 2; ++nf) {                                           \
      const char* br = Bb_ + (wn * 64 + (NH) * 32 + nf * 16 + fr) * 128;       \
      b[nf][0] = *(const bf16x8*)(br + cb0);                                   \
      b[nf][1] = *(const bf16x8*)(br + cb1);                                   \
    }                                                                          \
    STAGE(SG, STILE, SHALF, SLDS);                                             \
    __builtin_amdgcn_s_barrier();                                              \
    __builtin_amdgcn_sched_barrier(0);                                         \
    __builtin_amdgcn_s_setprio(1);                                             \
    _Pragma("unroll")                                                          \
    for (int mf = 0; mf < 4; ++mf) {                                           \
      _Pragma("unroll")                                                        \
      for (int nf = 0; nf < 2; ++nf) {                                         \
        acc[(MH)*4 + mf][(NH)*2 + nf] = __builtin_amdgcn_mfma_f32_16x16x32_bf16( \
            a[mf][0], b[nf][0], acc[(MH)*4 + mf][(NH)*2 + nf], 0, 0, 0);       \
        acc[(MH)*4 + mf][(NH)*2 + nf] = __builtin_amdgcn_mfma_f32_16x16x32_bf16( \
            a[mf][1], b[nf][1], acc[(MH)*4 + mf][(NH)*2 + nf], 0, 0, 0);       \
      }                                                                        \
    }                                                                          \
    __builtin_amdgcn_s_setprio(0);                                             \
    if (W2) asm volatile("s_waitcnt vmcnt(2)" ::: "memory");                   \
    __builtin_amdgcn_s_barrier();                                              \
    __builtin_amdgcn_sched_barrier(0);                                         \
  }

  // 16 K-tiles (K=1024, BK=64); 8 iterations x 2 tiles. Stage schedule:
  // ph0:A(t+1)h1->b1  ph1:B(t+1)h0->b1  ph2:B(t+1)h1->b1  ph3:A(t+2)h0->b0
  // ph4:A(t+2)h1->b0  ph5:B(t+2)h0->b0  ph6:B(t+2)h1->b0  ph7:A(t+3)h0->b1
  // vmcnt(2) before BAR2 of ph3 (buf1 ready for ph4) and ph7 (buf0 ready
  // for next ph0); wait-then-barrier makes the per-wave count block-wide.
  for (int j = 0; j < 8; ++j) {
    const int t0 = 2 * j;
    PHASE(0, 0, 0, true,  Ag, ldsA1, t0 + 1, 1, false);
    PHASE(0, 0, 1, false, Bg, ldsB1, t0 + 1, 0, false);
    PHASE(0, 1, 0, true,  Bg, ldsB1, t0 + 1, 1, false);
    PHASE(0, 1, 1, false, Ag, ldsA0, t0 + 2, 0, true);
    PHASE(1, 0, 0, true,  Ag, ldsA0, t0 + 2, 1, false);
    PHASE(1, 0, 1, false, Bg, ldsB0, t0 + 2, 0, false);
    PHASE(1, 1, 0, true,  Bg, ldsB0, t0 + 2, 1, false);
    PHASE(1, 1, 1, false, Ag, ldsA1, t0 + 3, 0, true);
  }
#undef PHASE

  asm volatile("s_waitcnt vmcnt(0)" ::: "memory");

  // ---- epilogue: scatter q (scaled), k, v (bit2<->3 permuted cols) ----
  const int which = bn >> 2;                 // 0=q 1=k 2=v (block-uniform)
  const int head = (bn & 3) * 4 + wn;
  const int batch = bm >> 3;
  const size_t bh = (size_t)batch * 16 + head;
  const int rbase = (bm & 7) * 256 + wm * 128 + ((lane >> 4) << 2);
#pragma unroll
  for (int nf16 = 0; nf16 < 4; ++nf16) {
    const int dd = nf16 * 16 + fr;
    const float bv = bias[bn * 256 + wn * 64 + dd];
#pragma unroll
    for (int mf = 0; mf < 8; ++mf) {
      const int nr0 = rbase + mf * 16;
      if (which == 2) {
        int nper = (nr0 & ~12) | ((nr0 & 4) << 1) | ((nr0 & 8) >> 1);
        s16x4 pk;
#pragma unroll
        for (int r = 0; r < 4; ++r) pk[r] = f2bf(acc[mf][nf16][r] + bv);
        *(s16x4*)(vto + (bh * 64 + dd) * 2048 + nper) = pk;
      } else if (which == 0) {
        short* dst = qo + (bh * 2048 + nr0) * 64 + dd;
#pragma unroll
        for (int r = 0; r < 4; ++r)
          dst[(size_t)r * 64] = f2bf((acc[mf][nf16][r] + bv) * (0.125f * LOG2E));
      } else {
        short* dst = ko + (bh * 2048 + nr0) * 64 + dd;
#pragma unroll
        for (int r = 0; r < 4; ++r) dst[(size_t)r * 64] = f2bf(acc[mf][nf16][r] + bv);
      }
    }
  }
}

// ---------------- proj GEMM: 128^2 2-phase (unchanged, passing) ----------------
template <int EPI>
__global__ __launch_bounds__(256, 2) void gemm_bt(
    const short* __restrict__ A, const short* __restrict__ Bm,
    const float* __restrict__ bias, int K,
    float* __restrict__ outf) {
  __shared__ __align__(16) char smem[16384];
  char* As = smem;
  char* Bs = smem + 8192;
  const int tid = threadIdx.x, lane = tid & 63, w = tid >> 6;
  const int wm = w >> 1, wn = w & 1;
  const int bm = blockIdx.y, bn = blockIdx.x;

  f32x4 acc[4][4];
  const f32x4 z4 = {0.f, 0.f, 0.f, 0.f};
#pragma unroll
  for (int m = 0; m < 4; ++m)
#pragma unroll
    for (int n = 0; n < 4; ++n) acc[m][n] = z4;

  const short* Abase = A + (size_t)bm * 128 * K;
  const short* Bbase = Bm + (size_t)bn * 128 * K;

  for (int k0 = 0; k0 < K; k0 += 32) {
#pragma unroll
    for (int j = 0; j < 2; ++j) {
      int ia = w * 2 + j;
      int row = ia * 16 + (lane >> 2);
      int cl = (lane & 3) ^ (row & 3);
      gload_lds16(Abase + (size_t)row * K + k0 + cl * 8, As + ia * 1024);
      gload_lds16(Bbase + (size_t)row * K + k0 + cl * 8, Bs + ia * 1024);
    }
    __syncthreads();

    bf16x8 af[4], bf[4];
#pragma unroll
    for (int m = 0; m < 4; ++m) {
      int r = wm * 64 + m * 16 + (lane & 15);
      af[m] = *(const bf16x8*)(As + r * 64 + ((((lane >> 4)) ^ (r & 3)) << 4));
    }
#pragma unroll
    for (int n = 0; n < 4; ++n) {
      int r = wn * 64 + n * 16 + (lane & 15);
      bf[n] = *(const bf16x8*)(Bs + r * 64 + ((((lane >> 4)) ^ (r & 3)) << 4));
    }
#pragma unroll
    for (int m = 0; m < 4; ++m)
#pragma unroll
      for (int n = 0; n < 4; ++n)
        acc[m][n] = __builtin_amdgcn_mfma_f32_16x16x32_bf16(af[m], bf[n], acc[m][n], 0, 0, 0);
    __syncthreads();
  }

#pragma unroll
  for (int nf = 0; nf < 4; ++nf) {
    int gn = bn * 128 + wn * 64 + nf * 16 + (lane & 15);
    float bv = bias[gn];
#pragma unroll
    for (int m = 0; m < 4; ++m) {
      int gm0 = bm * 128 + wm * 64 + m * 16 + ((lane >> 4) << 2);
      float* dst = outf + (size_t)gm0 * 1024 + gn;
#pragma unroll
      for (int r = 0; r < 4; ++r) dst[(size_t)r * 1024] = acc[m][nf][r] + bv;
    }
  }
}

// two PV B-frags (K=16 each) from one exp'd s-vector (V pre-permuted)
#define BUILD_PF2(d0, d1, sv)                                                  \
  {                                                                            \
    u32x4 w0_ = {cvtpk_bf16(sv[0], sv[1]), cvtpk_bf16(sv[2], sv[3]),           \
                 cvtpk_bf16(sv[4], sv[5]), cvtpk_bf16(sv[6], sv[7])};          \
    d0 = __builtin_bit_cast(bf16x8, w0_);                                      \
    u32x4 w1_ = {cvtpk_bf16(sv[8], sv[9]), cvtpk_bf16(sv[10], sv[11]),         \
                 cvtpk_bf16(sv[12], sv[13]), cvtpk_bf16(sv[14], sv[15])};      \
    d1 = __builtin_bit_cast(bf16x8, w1_);                                      \
  }

// ---------------- flash attention (R11, unchanged) ----------------
__global__ __launch_bounds__(256, 3) void attn_kernel(
    const short* __restrict__ q, const short* __restrict__ kk,
    const short* __restrict__ vt, short* __restrict__ ao) {
  __shared__ __align__(16) char smem[32768];
  const int tid = threadIdx.x, lane = tid & 63, w = tid >> 6;
  const int r31 = lane & 31, h = lane >> 5;
  const int id = blockIdx.x;
  const int xcd = id & 7, p = id >> 3;
  const int bh = xcd * 8 + (p >> 4);
  const int qblk = p & 15;
  const int q0 = qblk * 128 + w * 32;

  const short* qptr = q + ((size_t)bh * 2048 + q0 + r31) * 64 + h * 8;
  const short* kgl = kk + (size_t)bh * 2048 * 64;
  const short* vgl = vt + (size_t)bh * 64 * 2048;

  const int srow = w * 16 + (lane >> 3);
  const int scol = ((lane & 7) * 8) ^ ((lane >> 3) << 3);
  const int ldst = w * 2048;

  bf16x8 qf[4];
#pragma unroll
  for (int dk = 0; dk < 4; ++dk) qf[dk] = *(const bf16x8*)(qptr + dk * 16);

  f32x16 o0, o1;
#pragma unroll
  for (int e = 0; e < 16; ++e) { o0[e] = 0.f; o1[e] = 0.f; }
  float ls[4];
#pragma unroll
  for (int e = 0; e < 4; ++e) ls[e] = 0.f;

#pragma unroll
  for (int j = 0; j < 2; ++j) {
    gload_lds16(kgl + (size_t)(srow + j * 8) * 64 + scol, smem + ldst + j * 1024);
    gload_lds16(vgl + (size_t)(srow + j * 8) * 2048 + scol, smem + 8192 + ldst + j * 1024);
  }
  __syncthreads();

  int cur = 0;
  for (int t = 0; t < 2048; t += 64) {
    const char* Kb = smem + cur * 16384;
    const char* Vb = smem + cur * 16384 + 8192;

    if (t + 64 < 2048) {
      char* nb = (char*)smem + (cur ^ 1) * 16384;
#pragma unroll
      for (int j = 0; j < 2; ++j) {
        gload_lds16(kgl + (size_t)(t + 64 + srow + j * 8) * 64 + scol, nb + ldst + j * 1024);
        gload_lds16(vgl + (size_t)(srow + j * 8) * 2048 + (t + 64) + scol, nb + 8192 + ldst + j * 1024);
      }
    }

    bf16x8 kf0[4], kf1[4];
#pragma unroll
    for (int dk = 0; dk < 4; ++dk) {
      int cb = (dk * 32 + h * 16) ^ ((r31 & 7) << 4);
      kf0[dk] = *(const bf16x8*)(Kb + r31 * 128 + cb);
      kf1[dk] = *(const bf16x8*)(Kb + (32 + r31) * 128 + cb);
    }

    f32x16 s0, s1;
#pragma unroll
    for (int e = 0; e < 16; ++e) { s0[e] = 0.f; s1[e] = 0.f; }
#pragma unroll
    for (int dk = 0; dk < 4; ++dk) {
      s0 = __builtin_amdgcn_mfma_f32_32x32x16_bf16(kf0[dk], qf[dk], s0, 0, 0, 0);
      s1 = __builtin_amdgcn_mfma_f32_32x32x16_bf16(kf1[dk], qf[dk], s1, 0, 0, 0);
    }

#pragma unroll
    for (int e = 0; e < 16; ++e) {
      s0[e] = exp2_hw(s0[e]);
      s1[e] = exp2_hw(s1[e]);
    }
#pragma unroll
    for (int e = 0; e < 4; ++e) {
      float t0 = (s0[e] + s0[e + 4]) + (s0[e + 8] + s0[e + 12]);
      float t1 = (s1[e] + s1[e + 4]) + (s1[e + 8] + s1[e + 12]);
      ls[e] += t0 + t1;
    }

    bf16x8 pf0, pf1, pf2, pf3;
    BUILD_PF2(pf0, pf1, s0);
    BUILD_PF2(pf2, pf3, s1);

    {
      bf16x8 v00, v10, v01, v11;
      int cb0 = (0 * 32 + h * 16) ^ ((r31 & 7) << 4);
      int cb1 = (1 * 32 + h * 16) ^ ((r31 & 7) << 4);
      v00 = *(const bf16x8*)(Vb + r31 * 128 + cb0);
      v10 = *(const bf16x8*)(Vb + (32 + r31) * 128 + cb0);
      v01 = *(const bf16x8*)(Vb + r31 * 128 + cb1);
      v11 = *(const bf16x8*)(Vb + (32 + r31) * 128 + cb1);
      o0 = __builtin_amdgcn_mfma_f32_32x32x16_bf16(v00, pf0, o0, 0, 0, 0);
      o1 = __builtin_amdgcn_mfma_f32_32x32x16_bf16(v10, pf0, o1, 0, 0, 0);
      o0 = __builtin_amdgcn_mfma_f32_32x32x16_bf16(v01, pf1, o0, 0, 0, 0);
      o1 = __builtin_amdgcn_mfma_f32_32x32x16_bf16(v11, pf1, o1, 0, 0, 0);
    }
    {
      bf16x8 v02, v12, v03, v13;
      int cb2 = (2 * 32 + h * 16) ^ ((r31 & 7) << 4);
      int cb3 = (3 * 32 + h * 16) ^ ((r31 & 7) << 4);
      v02 = *(const bf16x8*)(Vb + r31 * 128 + cb2);
      v12 = *(const bf16x8*)(Vb + (32 + r31) * 128 + cb2);
      v03 = *(const bf16x8*)(Vb + r31 * 128 + cb3);
      v13 = *(const bf16x8*)(Vb + (32 + r31) * 128 + cb3);
      o0 = __builtin_amdgcn_mfma_f32_32x32x16_bf16(v02, pf2, o0, 0, 0, 0);
      o1 = __builtin_amdgcn_mfma_f32_32x32x16_bf16(v12, pf2, o1, 0, 0, 0);
      o0 = __builtin_amdgcn_mfma_f32_32x32x16_bf16(v03, pf3, o0, 0, 0, 0);
      o1 = __builtin_amdgcn_mfma_f32_32x32x16_bf16(v13, pf3, o1, 0, 0, 0);
    }

    __syncthreads();
    cur ^= 1;
  }

  float lsum = (ls[0] + ls[1]) + (ls[2] + ls[3]);
  lsum += __shfl_xor(lsum, 32);

  const int b = bh >> 4, hd = bh & 15;
  float inv = 1.f / lsum;
  short* orow = ao + ((size_t)b * 2048 + q0 + r31) * 1024 + hd * 64;
#pragma unroll
  for (int s2 = 0; s2 < 4; ++s2) {
    s16x4 pk0, pk1;
#pragma unroll
    for (int r = 0; r < 4; ++r) {
      pk0[r] = f2bf(o0[4 * s2 + r] * inv);
      pk1[r] = f2bf(o1[4 * s2 + r] * inv);
    }
    *(s16x4*)(orow + 8 * s2 + 4 * h) = pk0;
    *(s16x4*)(orow + 32 + 8 * s2 + 4 * h) = pk1;
  }
}

// ---------------- launch ----------------
extern "C" void kernel_launch(void* const* d_in, const int* in_sizes, int n_in,
                              void* d_out, int out_size, void* d_ws, size_t ws_size,
                              hipStream_t stream) {
  const float* x = (const float*)d_in[0];
  const float* qkv_w = (const float*)d_in[1];
  const float* qkv_b = (const float*)d_in[2];
  const float* proj_w = (const float*)d_in[3];
  const float* proj_b = (const float*)d_in[4];
  float* out = (float*)d_out;

  char* ws = (char*)d_ws;
  short* xb    = (short*)(ws + 0);          // 16 MB  [8192][1024]
  short* wqkv  = (short*)(ws + 16777216);   // 6 MB   [3072][1024]
  short* wproj = (short*)(ws + 23068672);   // 2 MB   [1024][1024]
  short* qb    = (short*)(ws + 25165824);   // 16 MB  [B,H,N,Hd]
  short* kb    = (short*)(ws + 41943040);   // 16 MB  [B,H,N,Hd]
  short* vtb   = (short*)(ws + 58720256);   // 16 MB  [B,H,Hd,N] (perm'd cols)
  short* aob   = (short*)(ws + 75497472);   // 16 MB  [B,N,D]

  cvt_f32_bf16<<<8192, 256, 0, stream>>>(x, xb, 2097152);
  cvt_f32_bf16<<<3072, 256, 0, stream>>>(qkv_w, wqkv, 786432);
  cvt_f32_bf16<<<1024, 256, 0, stream>>>(proj_w, wproj, 262144);

  gemm_qkv<<<dim3(12, 32), 512, 0, stream>>>(xb, wqkv, qkv_b, qb, kb, vtb);
  attn_kernel<<<1024, 256, 0, stream>>>(qb, kb, vtb, aob);
  gemm_bt<1><<<dim3(8, 64), 256, 0, stream>>>(aob, wproj, proj_b, 1024, out);
}